// Round 5
// baseline (180.591 us; speedup 1.0000x reference)
//
#include <hip/hip_runtime.h>
#include <hip/hip_bf16.h>
#include <math.h>

// ---------------------------------------------------------------------------
// Q_Mlp: x0 -> int4-quant -> GEMM1(K=768) -> dequant+GELU+clip -> int4-quant
//        -> GEMM2(K=3072) -> dequant+bias -> out (f32)
// Quantized operands are integers in [-8,7]: exact in int8. i8 MFMA
// (16x16x64, 2x bf16 rate) with i32 accumulation (max |acc| < 2^18, exact).
//
// GEMM structure: single-buffered 2-barrier loop (round-3 proven; the r4
// double-buffer REGRESSED: 64KB LDS -> 2 blocks/CU < grid's 3/CU -> 1.5
// execution rounds). GEMM2 is latency-bound + grid-starved (N=768, BN=128
// -> only 3 blocks/CU): fix by BN=64 -> 1536 blocks = 6/CU, 24KB LDS.
//
// LDS bank-conflict fix (T2, rule #21 both-sides involution), verified 1.4e7->0:
//   col ^= ((row&7)<<4); staging pre-swizzles the GLOBAL source col
//   (global_load_lds dest stays linear); fragment read applies the same XOR.
//   Both reduce to lane constants -> zero instruction cost.
//
// Workspace layout (bytes):
//   [0,256)              : a1, a2, inv_a2, 0.5*inv_a2 (f32)
//   [256, +12582912)     : xq  i8 [16384][768]
//   [12583168, +2359296) : wq1 i8 [3072][768]
//   [14942464, +2359296) : wq2 i8 [768][3072]
//   [17301760, +50331648): hq  i8 [16384][3072]
// ---------------------------------------------------------------------------

typedef __attribute__((ext_vector_type(4))) int i32x4;

__device__ __forceinline__ void gload_lds16(const void* g, void* l) {
  __builtin_amdgcn_global_load_lds(
      (const __attribute__((address_space(1))) void*)g,
      (__attribute__((address_space(3))) void*)l, 16, 0, 0);
}

// quantize: round-half-even(clip(x/a, -8, 7)) -> int in [-8,7]
__device__ __forceinline__ int q4_i8(float x, float a) {
  float t = x / a;  // IEEE div, matches numpy
  t = fminf(fmaxf(t, -8.0f), 7.0f);
  t = rintf(t);  // RNE, matches np.round
  return (int)t;
}

// ---- means of alpha_a1 (768) and alpha_a2 (3072), f64 accumulate ----------
__global__ void means_k(const float* __restrict__ v1, int n1,
                        const float* __restrict__ v2, int n2,
                        float* __restrict__ out) {
  const float* src = blockIdx.x ? v2 : v1;
  const int n = blockIdx.x ? n2 : n1;
  __shared__ double red[256];
  double s = 0.0;
  for (int i = threadIdx.x; i < n; i += 256) s += (double)src[i];
  red[threadIdx.x] = s;
  __syncthreads();
  for (int st = 128; st > 0; st >>= 1) {
    if (threadIdx.x < st) red[threadIdx.x] += red[threadIdx.x + st];
    __syncthreads();
  }
  if (threadIdx.x == 0) {
    float m = (float)(red[0] / (double)n);
    out[blockIdx.x] = m;
    if (blockIdx.x == 1) {
      out[2] = 1.0f / m;
      out[3] = 0.5f * (1.0f / m);
    }
  }
}

// ---- quantize activations x0 -> xq i8 -------------------------------------
__global__ void quant_x_k(const float* __restrict__ x,
                          unsigned* __restrict__ xq,
                          const float* __restrict__ means, int n4) {
  int i = blockIdx.x * blockDim.x + threadIdx.x;
  if (i >= n4) return;
  const float a = means[0];
  float4 v = ((const float4*)x)[i];
  unsigned u = (q4_i8(v.x, a) & 0xFF) | ((q4_i8(v.y, a) & 0xFF) << 8) |
               ((q4_i8(v.z, a) & 0xFF) << 16) | ((q4_i8(v.w, a) & 0xFF) << 24);
  xq[i] = u;
}

// ---- quantize weights [R][C] with per-row alpha ---------------------------
__global__ void quant_w_k(const float* __restrict__ w,
                          const float* __restrict__ alpha,
                          unsigned* __restrict__ wq, int C, int n4) {
  int i = blockIdx.x * blockDim.x + threadIdx.x;
  if (i >= n4) return;
  int row = (i * 4) / C;
  const float a = alpha[row];
  float4 v = ((const float4*)w)[i];
  unsigned u = (q4_i8(v.x, a) & 0xFF) | ((q4_i8(v.y, a) & 0xFF) << 8) |
               ((q4_i8(v.z, a) & 0xFF) << 16) | ((q4_i8(v.w, a) & 0xFF) << 24);
  wq[i] = u;
}

// ---- GEMM: C[M,N] = A[M,K] * B[N,K]^T, i8 MFMA 16x16x64, BK=128 -----------
// BM=128 fixed, BN in {128,64}. 256 threads, 4 waves in 2x2 over (128, BN):
// wave tile 64 x BN/2, NF = BN/32 n-fragments.
// EPI==1: dequant+bias -> gelu(exact-erf approx) -> quant(a2) -> i8 hq
// EPI==2: dequant(a2,alpha_w2)+bias -> f32 out (bit-exact numpy chain)
template <int EPI, int BN, int LB>
__global__ __launch_bounds__(256, LB) void gemm_k(
    const signed char* __restrict__ A, const signed char* __restrict__ B,
    const float* __restrict__ alphaw, const float* __restrict__ bias,
    const float* __restrict__ means, signed char* __restrict__ out_b,
    float* __restrict__ out_f, int N, int K) {
  constexpr int NF = BN / 32;  // n fragments per wave (and B chunks per wave)
  __shared__ __align__(16) signed char sA[128 * 128];
  __shared__ __align__(16) signed char sB[BN * 128];
  const int tid = threadIdx.x;
  const int w = tid >> 6;
  const int l = tid & 63;
  const int wm = w >> 1, wn = w & 1;
  const long bm0 = (long)blockIdx.y * 128;
  const long bn0 = (long)blockIdx.x * BN;

  i32x4 acc[4][NF] = {};

  const int srow = l >> 3;                        // row-within-chunk 0..7
  const int scol = ((l & 7) * 16) ^ (srow << 4);  // pre-swizzled src col
  const int rsw = (l & 7) << 4;                   // read-side XOR

  // per-thread global base pointers (chunk rows)
  const signed char* gA = A + (bm0 + w * 32 + srow) * (long)K + scol;
  const signed char* gB = B + (bn0 + w * 8 * NF + srow) * (long)K + scol;

  for (int kt = 0; kt < K; kt += 128) {
    __syncthreads();  // previous tile's LDS reads done
#pragma unroll
    for (int i = 0; i < 4; ++i)  // A: 16 chunks, 4 per wave
      gload_lds16(gA + (long)i * 8 * K + kt, sA + (w * 4 + i) * 1024);
#pragma unroll
    for (int j = 0; j < NF; ++j)  // B: BN/8 chunks, NF per wave
      gload_lds16(gB + (long)j * 8 * K + kt, sB + (w * NF + j) * 1024);
    __syncthreads();  // staging visible (compiler drains vmcnt)
#pragma unroll
    for (int kk = 0; kk < 2; ++kk) {
      const int kc = (kk * 64 + (l >> 4) * 16) ^ rsw;  // swizzled k-col
      i32x4 af[4], bg[NF];
#pragma unroll
      for (int m = 0; m < 4; ++m)
        af[m] = *(const i32x4*)&sA[(wm * 64 + m * 16 + (l & 15)) * 128 + kc];
#pragma unroll
      for (int n = 0; n < NF; ++n)
        bg[n] = *(const i32x4*)&sB[(wn * (BN / 2) + n * 16 + (l & 15)) * 128 +
                                   kc];
#pragma unroll
      for (int m = 0; m < 4; ++m)
#pragma unroll
        for (int n = 0; n < NF; ++n)
          acc[m][n] = __builtin_amdgcn_mfma_i32_16x16x64_i8(af[m], bg[n],
                                                            acc[m][n], 0, 0, 0);
    }
  }

  const float a1 = means[0];
  const float a2 = means[1];
  const float half_inv_a2 = means[3];

  // hoist per-column constants (NF columns per thread)
  float awc[NF], bsc[NF];
  const int cc0 = (int)bn0 + wn * (BN / 2) + (l & 15);
#pragma unroll
  for (int n = 0; n < NF; ++n) {
    awc[n] = alphaw[cc0 + n * 16];
    bsc[n] = bias[cc0 + n * 16];
  }

  const int r0 = (int)bm0 + wm * 64 + (l >> 4) * 4;

  if (EPI == 1) {
    float awa1[NF];
#pragma unroll
    for (int n = 0; n < NF; ++n) awa1[n] = awc[n] * a1;
#pragma unroll
    for (int m = 0; m < 4; ++m) {
#pragma unroll
      for (int rg = 0; rg < 4; ++rg) {
        const int r = r0 + m * 16 + rg;
        signed char* prow = out_b + (size_t)r * N + cc0;
#pragma unroll
        for (int n = 0; n < NF; ++n) {
          const float f = (float)acc[m][n][rg];  // exact: |acc| < 2^18
          const float t = fmaf(f, awa1[n], bsc[n]);
          // exact-formula GELU via A&S 7.1.26 erf (|err|<=1.5e-7)
          const float x = t * 0.70710678118654752f;
          const float az = fabsf(x);
          const float rr = __builtin_amdgcn_rcpf(fmaf(0.3275911f, az, 1.0f));
          float p = fmaf(rr, 1.061405429f, -1.453152027f);
          p = fmaf(rr, p, 1.421413741f);
          p = fmaf(rr, p, -0.284496736f);
          p = fmaf(rr, p, 0.254829592f);
          p = p * rr;
          const float e = __expf(-az * az);
          float er = fmaf(-p, e, 1.0f);
          er = copysignf(er, x);
          // +/-10 clip dropped: 10/a2 > 7 always, saturation identical
          float qv = t * (1.0f + er) * half_inv_a2;
          qv = fminf(fmaxf(qv, -8.0f), 7.0f);
          qv = rintf(qv);
          prow[n * 16] = (signed char)(int)qv;
        }
      }
    }
  } else {
#pragma unroll
    for (int m = 0; m < 4; ++m) {
#pragma unroll
      for (int rg = 0; rg < 4; ++rg) {
        const int r = r0 + m * 16 + rg;
        float* prow = out_f + (size_t)r * N + cc0;
#pragma unroll
        for (int n = 0; n < NF; ++n) {
          const float f = (float)acc[m][n][rg];
          // bit-exact numpy chain: ((x*aw)*a2) + b, no FMA contraction
          float t = __fmul_rn(f, awc[n]);
          t = __fmul_rn(t, a2);
          t = __fadd_rn(t, bsc[n]);
          prow[n * 16] = t;
        }
      }
    }
  }
}

extern "C" void kernel_launch(void* const* d_in, const int* in_sizes, int n_in,
                              void* d_out, int out_size, void* d_ws,
                              size_t ws_size, hipStream_t stream) {
  const float* x0 = (const float*)d_in[0];
  const float* w1 = (const float*)d_in[1];
  const float* b1 = (const float*)d_in[2];
  const float* aw1 = (const float*)d_in[3];
  const float* aa1 = (const float*)d_in[4];
  const float* w2 = (const float*)d_in[5];
  const float* b2 = (const float*)d_in[6];
  const float* aw2 = (const float*)d_in[7];
  const float* aa2 = (const float*)d_in[8];

  char* ws = (char*)d_ws;
  float* means = (float*)ws;
  signed char* xq = (signed char*)(ws + 256);
  signed char* wq1 = (signed char*)(ws + 12583168);
  signed char* wq2 = (signed char*)(ws + 14942464);
  signed char* hq = (signed char*)(ws + 17301760);

  // 1) means of alpha_a1 / alpha_a2 (+ 1/a2, 0.5/a2)
  means_k<<<2, 256, 0, stream>>>(aa1, 768, aa2, 3072, means);
  // 2) quantize activations and weights to i8
  quant_x_k<<<12288, 256, 0, stream>>>(x0, (unsigned*)xq, means, 3145728);
  quant_w_k<<<2304, 256, 0, stream>>>(w1, aw1, (unsigned*)wq1, 768, 589824);
  quant_w_k<<<2304, 256, 0, stream>>>(w2, aw2, (unsigned*)wq2, 3072, 589824);
  // 3) GEMM1 [16384,768]x[3072,768]^T + gelu + requant -> hq (i8)
  //    BN=128: grid 24x128=3072 blocks (12/CU demand, LDS caps 5)
  dim3 g1(24, 128);
  gemm_k<1, 128, 5><<<g1, 256, 0, stream>>>(xq, wq1, aw1, b1, means, hq,
                                            nullptr, 3072, 768);
  // 4) GEMM2 [16384,3072]x[768,3072]^T + bias -> f32 out
  //    BN=64: grid 12x128=1536 blocks = 6/CU (was 3/CU at BN=128 -> starved)
  dim3 g2(12, 128);
  gemm_k<2, 64, 6><<<g2, 256, 0, stream>>>(hq, wq2, aw2, b2, means, nullptr,
                                           (float*)d_out, 768, 3072);
}

// Round 6
// 136.470 us; speedup vs baseline: 1.3233x; 1.3233x over previous
//
#include <hip/hip_runtime.h>
#include <hip/hip_bf16.h>
#include <math.h>

// ---------------------------------------------------------------------------
// Q_Mlp: x0 -> int4-quant -> GEMM1(K=768) -> dequant+GELU+clip -> int4-quant
//        -> GEMM2(K=3072) -> dequant+bias -> out (f32)
// Quantized operands are integers in [-8,7]: exact in int8. i8 MFMA
// (16x16x64, 2x bf16 rate) with i32 accumulation (max |acc| < 2^18, exact).
//
// GEMM1: round-3 proven config (256t, BN=128, LB=4, single-buffer 2-barrier).
// GEMM2: supply-limited (N=768 -> 768 blocks = exactly 3/CU); r5's BN=64
//   regressed (capacity 5 < supply 6 -> tail). This round: 512 threads /
//   8 waves on the same 128x128 tile -> 24 resident waves/CU (6/SIMD) with
//   unchanged grid packing; per-wave work halves (acc[2][4]).
//
// LDS bank-conflict fix (T2, rule #21 both-sides involution), verified 1.4e7->0:
//   col ^= ((row&7)<<4); staging pre-swizzles the GLOBAL source col
//   (global_load_lds dest stays linear); fragment read applies the same XOR.
//   Both reduce to lane constants -> zero instruction cost.
//
// Workspace layout (bytes):
//   [0,256)              : a1, a2, inv_a2, 0.5*inv_a2 (f32)
//   [256, +12582912)     : xq  i8 [16384][768]
//   [12583168, +2359296) : wq1 i8 [3072][768]
//   [14942464, +2359296) : wq2 i8 [768][3072]
//   [17301760, +50331648): hq  i8 [16384][3072]
// ---------------------------------------------------------------------------

typedef __attribute__((ext_vector_type(4))) int i32x4;

__device__ __forceinline__ void gload_lds16(const void* g, void* l) {
  __builtin_amdgcn_global_load_lds(
      (const __attribute__((address_space(1))) void*)g,
      (__attribute__((address_space(3))) void*)l, 16, 0, 0);
}

// quantize: round-half-even(clip(x/a, -8, 7)) -> int in [-8,7]
__device__ __forceinline__ int q4_i8(float x, float a) {
  float t = x / a;  // IEEE div, matches numpy
  t = fminf(fmaxf(t, -8.0f), 7.0f);
  t = rintf(t);  // RNE, matches np.round
  return (int)t;
}

// ---- means of alpha_a1 (768) and alpha_a2 (3072), f64 accumulate ----------
__global__ void means_k(const float* __restrict__ v1, int n1,
                        const float* __restrict__ v2, int n2,
                        float* __restrict__ out) {
  const float* src = blockIdx.x ? v2 : v1;
  const int n = blockIdx.x ? n2 : n1;
  __shared__ double red[256];
  double s = 0.0;
  for (int i = threadIdx.x; i < n; i += 256) s += (double)src[i];
  red[threadIdx.x] = s;
  __syncthreads();
  for (int st = 128; st > 0; st >>= 1) {
    if (threadIdx.x < st) red[threadIdx.x] += red[threadIdx.x + st];
    __syncthreads();
  }
  if (threadIdx.x == 0) {
    float m = (float)(red[0] / (double)n);
    out[blockIdx.x] = m;
    if (blockIdx.x == 1) {
      out[2] = 1.0f / m;
      out[3] = 0.5f * (1.0f / m);
    }
  }
}

// ---- quantize activations x0 -> xq i8 -------------------------------------
__global__ void quant_x_k(const float* __restrict__ x,
                          unsigned* __restrict__ xq,
                          const float* __restrict__ means, int n4) {
  int i = blockIdx.x * blockDim.x + threadIdx.x;
  if (i >= n4) return;
  const float a = means[0];
  float4 v = ((const float4*)x)[i];
  unsigned u = (q4_i8(v.x, a) & 0xFF) | ((q4_i8(v.y, a) & 0xFF) << 8) |
               ((q4_i8(v.z, a) & 0xFF) << 16) | ((q4_i8(v.w, a) & 0xFF) << 24);
  xq[i] = u;
}

// ---- quantize weights [R][C] with per-row alpha ---------------------------
__global__ void quant_w_k(const float* __restrict__ w,
                          const float* __restrict__ alpha,
                          unsigned* __restrict__ wq, int C, int n4) {
  int i = blockIdx.x * blockDim.x + threadIdx.x;
  if (i >= n4) return;
  int row = (i * 4) / C;
  const float a = alpha[row];
  float4 v = ((const float4*)w)[i];
  unsigned u = (q4_i8(v.x, a) & 0xFF) | ((q4_i8(v.y, a) & 0xFF) << 8) |
               ((q4_i8(v.z, a) & 0xFF) << 16) | ((q4_i8(v.w, a) & 0xFF) << 24);
  wq[i] = u;
}

// ---- GEMM1: C = A[M,K] * B[N,K]^T, 256t, 128x128 tile, BK=128 -------------
// dequant+bias -> gelu(exact-erf approx) -> quant(a2) -> i8 hq
__global__ __launch_bounds__(256, 4) void gemm1_k(
    const signed char* __restrict__ A, const signed char* __restrict__ B,
    const float* __restrict__ alphaw, const float* __restrict__ bias,
    const float* __restrict__ means, signed char* __restrict__ out_b, int N,
    int K) {
  __shared__ __align__(16) signed char sA[128 * 128];
  __shared__ __align__(16) signed char sB[128 * 128];
  const int tid = threadIdx.x;
  const int w = tid >> 6;
  const int l = tid & 63;
  const int wm = w >> 1, wn = w & 1;
  const long bm0 = (long)blockIdx.y * 128;
  const long bn0 = (long)blockIdx.x * 128;

  i32x4 acc[4][4] = {};

  const int srow = l >> 3;                        // row-within-chunk 0..7
  const int scol = ((l & 7) * 16) ^ (srow << 4);  // pre-swizzled src col
  const int rsw = (l & 7) << 4;                   // read-side XOR

  for (int kt = 0; kt < K; kt += 128) {
    __syncthreads();  // previous tile's LDS reads done
#pragma unroll
    for (int i = 0; i < 4; ++i) {
      const int c = w * 4 + i;  // chunk: 8 rows = 1KB of LDS
      const int row = c * 8 + srow;
      gload_lds16(A + (bm0 + row) * K + kt + scol, &sA[c * 1024]);
      gload_lds16(B + (bn0 + row) * K + kt + scol, &sB[c * 1024]);
    }
    __syncthreads();  // staging visible (compiler drains vmcnt)
#pragma unroll
    for (int kk = 0; kk < 2; ++kk) {
      const int kc = (kk * 64 + (l >> 4) * 16) ^ rsw;  // swizzled k-col
      i32x4 af[4], bg[4];
#pragma unroll
      for (int m = 0; m < 4; ++m)
        af[m] = *(const i32x4*)&sA[(wm * 64 + m * 16 + (l & 15)) * 128 + kc];
#pragma unroll
      for (int n = 0; n < 4; ++n)
        bg[n] = *(const i32x4*)&sB[(wn * 64 + n * 16 + (l & 15)) * 128 + kc];
#pragma unroll
      for (int m = 0; m < 4; ++m)
#pragma unroll
        for (int n = 0; n < 4; ++n)
          acc[m][n] = __builtin_amdgcn_mfma_i32_16x16x64_i8(af[m], bg[n],
                                                            acc[m][n], 0, 0, 0);
    }
  }

  const float a1 = means[0];
  const float half_inv_a2 = means[3];

  float awa1[4], bsc[4];
  const int cc0 = (int)bn0 + wn * 64 + (l & 15);
#pragma unroll
  for (int n = 0; n < 4; ++n) {
    awa1[n] = alphaw[cc0 + n * 16] * a1;
    bsc[n] = bias[cc0 + n * 16];
  }

  const int r0 = (int)bm0 + wm * 64 + (l >> 4) * 4;

#pragma unroll
  for (int m = 0; m < 4; ++m) {
#pragma unroll
    for (int rg = 0; rg < 4; ++rg) {
      const int r = r0 + m * 16 + rg;
      signed char* prow = out_b + (size_t)r * N + cc0;
#pragma unroll
      for (int n = 0; n < 4; ++n) {
        const float f = (float)acc[m][n][rg];  // exact: |acc| < 2^18
        const float t = fmaf(f, awa1[n], bsc[n]);
        // exact-formula GELU via A&S 7.1.26 erf (|err|<=1.5e-7)
        const float x = t * 0.70710678118654752f;
        const float az = fabsf(x);
        const float rr = __builtin_amdgcn_rcpf(fmaf(0.3275911f, az, 1.0f));
        float p = fmaf(rr, 1.061405429f, -1.453152027f);
        p = fmaf(rr, p, 1.421413741f);
        p = fmaf(rr, p, -0.284496736f);
        p = fmaf(rr, p, 0.254829592f);
        p = p * rr;
        const float e = __expf(-az * az);
        float er = fmaf(-p, e, 1.0f);
        er = copysignf(er, x);
        // +/-10 clip dropped: 10/a2 > 7 always, saturation identical
        float qv = t * (1.0f + er) * half_inv_a2;
        qv = fminf(fmaxf(qv, -8.0f), 7.0f);
        qv = rintf(qv);
        prow[n * 16] = (signed char)(int)qv;
      }
    }
  }
}

// ---- GEMM2: C = A[M,K] * B[N,K]^T, 512t / 8 waves, 128x128 tile, BK=128 ---
// Supply-limited grid (3 blocks/CU): 8 waves/block -> 24 waves/CU (6/SIMD).
// Wave (wm=w>>1 in 0..3, wn=w&1): tile 32x64, acc[2][4]. Each wave stages
// A-chunks {2w,2w+1} and B-chunks {2w,2w+1}.
// dequant(a2,alpha_w2)+bias -> f32 out (bit-exact numpy chain)
__global__ __launch_bounds__(512, 6) void gemm2_k(
    const signed char* __restrict__ A, const signed char* __restrict__ B,
    const float* __restrict__ alphaw, const float* __restrict__ bias,
    const float* __restrict__ means, float* __restrict__ out_f, int N, int K) {
  __shared__ __align__(16) signed char sA[128 * 128];
  __shared__ __align__(16) signed char sB[128 * 128];
  const int tid = threadIdx.x;
  const int w = tid >> 6;       // 0..7
  const int l = tid & 63;
  const int wm = w >> 1, wn = w & 1;
  const long bm0 = (long)blockIdx.y * 128;
  const long bn0 = (long)blockIdx.x * 128;

  i32x4 acc[2][4] = {};

  const int srow = l >> 3;                        // row-within-chunk 0..7
  const int scol = ((l & 7) * 16) ^ (srow << 4);  // pre-swizzled src col
  const int rsw = (l & 7) << 4;                   // read-side XOR

  const signed char* gA = A + (bm0 + w * 16 + srow) * (long)K + scol;
  const signed char* gB = B + (bn0 + w * 16 + srow) * (long)K + scol;

  for (int kt = 0; kt < K; kt += 128) {
    __syncthreads();  // previous tile's LDS reads done
#pragma unroll
    for (int i = 0; i < 2; ++i) {  // wave stages chunks 2w+i (A and B)
      gload_lds16(gA + (long)i * 8 * K + kt, &sA[(w * 2 + i) * 1024]);
      gload_lds16(gB + (long)i * 8 * K + kt, &sB[(w * 2 + i) * 1024]);
    }
    __syncthreads();  // staging visible (compiler drains vmcnt)
#pragma unroll
    for (int kk = 0; kk < 2; ++kk) {
      const int kc = (kk * 64 + (l >> 4) * 16) ^ rsw;  // swizzled k-col
      i32x4 af[2], bg[4];
#pragma unroll
      for (int m = 0; m < 2; ++m)
        af[m] = *(const i32x4*)&sA[(wm * 32 + m * 16 + (l & 15)) * 128 + kc];
#pragma unroll
      for (int n = 0; n < 4; ++n)
        bg[n] = *(const i32x4*)&sB[(wn * 64 + n * 16 + (l & 15)) * 128 + kc];
#pragma unroll
      for (int m = 0; m < 2; ++m)
#pragma unroll
        for (int n = 0; n < 4; ++n)
          acc[m][n] = __builtin_amdgcn_mfma_i32_16x16x64_i8(af[m], bg[n],
                                                            acc[m][n], 0, 0, 0);
    }
  }

  const float a2 = means[1];

  float awc[4], bsc[4];
  const int cc0 = (int)bn0 + wn * 64 + (l & 15);
#pragma unroll
  for (int n = 0; n < 4; ++n) {
    awc[n] = alphaw[cc0 + n * 16];
    bsc[n] = bias[cc0 + n * 16];
  }

  const int r0 = (int)bm0 + wm * 32 + (l >> 4) * 4;

#pragma unroll
  for (int m = 0; m < 2; ++m) {
#pragma unroll
    for (int rg = 0; rg < 4; ++rg) {
      const int r = r0 + m * 16 + rg;
      float* prow = out_f + (size_t)r * N + cc0;
#pragma unroll
      for (int n = 0; n < 4; ++n) {
        const float f = (float)acc[m][n][rg];
        // bit-exact numpy chain: ((x*aw)*a2) + b, no FMA contraction
        float t = __fmul_rn(f, awc[n]);
        t = __fmul_rn(t, a2);
        t = __fadd_rn(t, bsc[n]);
        prow[n * 16] = t;
      }
    }
  }
}

extern "C" void kernel_launch(void* const* d_in, const int* in_sizes, int n_in,
                              void* d_out, int out_size, void* d_ws,
                              size_t ws_size, hipStream_t stream) {
  const float* x0 = (const float*)d_in[0];
  const float* w1 = (const float*)d_in[1];
  const float* b1 = (const float*)d_in[2];
  const float* aw1 = (const float*)d_in[3];
  const float* aa1 = (const float*)d_in[4];
  const float* w2 = (const float*)d_in[5];
  const float* b2 = (const float*)d_in[6];
  const float* aw2 = (const float*)d_in[7];
  const float* aa2 = (const float*)d_in[8];

  char* ws = (char*)d_ws;
  float* means = (float*)ws;
  signed char* xq = (signed char*)(ws + 256);
  signed char* wq1 = (signed char*)(ws + 12583168);
  signed char* wq2 = (signed char*)(ws + 14942464);
  signed char* hq = (signed char*)(ws + 17301760);

  // 1) means of alpha_a1 / alpha_a2 (+ 1/a2, 0.5/a2)
  means_k<<<2, 256, 0, stream>>>(aa1, 768, aa2, 3072, means);
  // 2) quantize activations and weights to i8
  quant_x_k<<<12288, 256, 0, stream>>>(x0, (unsigned*)xq, means, 3145728);
  quant_w_k<<<2304, 256, 0, stream>>>(w1, aw1, (unsigned*)wq1, 768, 589824);
  quant_w_k<<<2304, 256, 0, stream>>>(w2, aw2, (unsigned*)wq2, 3072, 589824);
  // 3) GEMM1 [16384,768]x[3072,768]^T + gelu + requant -> hq (i8)
  dim3 g1(24, 128);
  gemm1_k<<<g1, 256, 0, stream>>>(xq, wq1, aw1, b1, means, hq, 3072, 768);
  // 4) GEMM2 [16384,3072]x[768,3072]^T + bias -> f32 out (512 threads)
  dim3 g2(6, 128);
  gemm2_k<<<g2, 512, 0, stream>>>(hq, wq2, aw2, b2, means, (float*)d_out, 768,
                                  3072);
}